// Round 9
// baseline (120.189 us; speedup 1.0000x reference)
//
#include <hip/hip_runtime.h>

// Problem constants
#define B_DIM   4096
#define C_DIM   128
#define TOPK    8
#define K_INST  16
#define P_IDS   256          // B/K_INST
#define N_DIM   32768        // B*TOPK
#define INV_TEMP 20.0f       // 1/0.05
#define EPS 1e-6f
#define TSZ 8192             // u16 elements per 16 KB A-tile LDS buffer (64 rows)

typedef unsigned short u16;
typedef __attribute__((ext_vector_type(8))) short bf16x8;
typedef __attribute__((ext_vector_type(4))) float f32x4;

struct alignas(8) U16x4 { u16 x, y, z, w; };

__device__ __forceinline__ u16 f2bf(float x) {
    union { float f; unsigned u; } v; v.f = x;
    unsigned r = v.u + 0x7fffu + ((v.u >> 16) & 1u);   // RTN-even
    return (u16)(r >> 16);
}

__device__ __forceinline__ void gload_lds16(const u16* g, u16* l) {
    __builtin_amdgcn_global_load_lds(
        (__attribute__((address_space(1))) void*)g,
        (__attribute__((address_space(3))) void*)l,
        16, 0, 0);
}

// ---------------- kernel 1: fp32 -> bf16 convert (A only, 1 MB out) ----------------
#define NA4 131072           // 4096*128/4
__global__ __launch_bounds__(256) void convert_bf16(const float4* __restrict__ fa,
                                                    u16* __restrict__ outA) {
    int i = blockIdx.x * 256 + threadIdx.x;
    float4 v = fa[i];
    U16x4 o = { f2bf(v.x), f2bf(v.y), f2bf(v.z), f2bf(v.w) };
    *(U16x4*)(outA + (size_t)i * 4) = o;
}

// ---------------- kernel 2: pipelined sim + per-block max/min ----------------
// grid (256 p, 4 h), block = 256 (4 waves as 2x2 over a 64x128 tile), 16 iters.
// R8 post-mortem: 64 KB LDS dbuf -> 2 blocks/CU (2 waves/SIMD) and the 512-block
// grid couldn't host more; half of all cycles idle (Mfma 28 + VALU 20). R9:
// 64-row tiles (16 KB x2 LDS), 1024 blocks, __launch_bounds__(256,3) ->
// 3 blocks/CU co-resident for latency hiding. Same swapped-operand MFMA
// (D = S^T tile: col=lane&15 indexes the A-row -> register fold + 2 shuffles,
// coalesced exclusive 64B-line stores), same XOR swizzle via global source
// address, same partial vmcnt drain before each barrier.
__global__ __launch_bounds__(256, 3) void phase1(const u16*  __restrict__ A,    // bf16 [4096][128]
                                                 const float* __restrict__ Bm32, // fp32 [32768][128]
                                                 float* __restrict__ pmax,      // [2][256][4096]
                                                 float* __restrict__ pmin)      // [2][4096]
{
    __shared__ u16 Als[2 * TSZ];      // 32 KB double buffer

    const int tid  = threadIdx.x;
    const int lane = tid & 63;
    const int wave = tid >> 6;
    const int wm   = wave >> 1;       // row half of 64 (0/1)
    const int wn   = wave & 1;        // col half (0/1)
    const int p    = blockIdx.x;      // identity col-block 0..255
    const int h    = blockIdx.y;      // row quarter: rows h*1024..+1023
    const int r    = lane & 15;
    const int g    = lane >> 4;

    // staging: thread stages slots s = j*256+tid (j=0..3); slot s holds global
    // chunk (row = s>>4, kc = (s&15)^((s>>4)&7)); kc is j-invariant (j*16%8==0).
    const int skc = (tid & 15) ^ ((tid >> 4) & 7);
    const u16* sbase = A + ((size_t)h * 1024 + (tid >> 4)) * C_DIM + skc * 8;

    // ---- prologue: DMA tile 0 -> buf0 (async) ----
    {
        u16* dst = &Als[tid * 8];
#pragma unroll
        for (int j = 0; j < 4; ++j)
            gload_lds16(sbase + (size_t)j * 16 * C_DIM, dst + j * 2048);
    }

    // ---- B fragments: fp32 -> bf16 in-register (one-time, 64 VGPRs) ----
    bf16x8 b[4][4];                   // [ni][kk]
    {
        const float* brow = Bm32 + (size_t)(p * 128 + wn * 64 + r) * C_DIM + g * 8;
#pragma unroll
        for (int ni = 0; ni < 4; ++ni)
#pragma unroll
            for (int kk = 0; kk < 4; ++kk) {
                const float* s0 = brow + (size_t)ni * 16 * C_DIM + kk * 32;
                float4 u0 = *(const float4*)s0;
                float4 u1 = *(const float4*)(s0 + 4);
                bf16x8 f;
                f[0] = (short)f2bf(u0.x); f[1] = (short)f2bf(u0.y);
                f[2] = (short)f2bf(u0.z); f[3] = (short)f2bf(u0.w);
                f[4] = (short)f2bf(u1.x); f[5] = (short)f2bf(u1.y);
                f[6] = (short)f2bf(u1.z); f[7] = (short)f2bf(u1.w);
                b[ni][kk] = f;
            }
    }

    const bool diag_blk = (h == (p >> 6));
    const int  itd      = (p & 63) >> 2;      // iter holding the anchor rows
    const int  dloc     = p & 3;              // 16-row group within the 64-row tile
    const int  wmsel    = dloc >> 1;
    const int  misel    = dloc & 1;
    float* const pmax_w = pmax + ((size_t)wn * P_IDS + p) * B_DIM;

    __builtin_amdgcn_s_waitcnt(0);            // prologue DMA + B loads done
    __builtin_amdgcn_s_barrier();

    int lofs = 0;
#pragma unroll 1
    for (int it = 0; it < 16; ++it) {
        // prefetch tile it+1 into the other buffer (overlaps this iter's compute)
        if (it < 15) {
            u16* dst = &Als[(lofs ^ TSZ) + tid * 8];
            const u16* src = sbase + (size_t)(it + 1) * 64 * C_DIM;
#pragma unroll
            for (int j = 0; j < 4; ++j)
                gload_lds16(src + (size_t)j * 16 * C_DIM, dst + j * 2048);
        }

        const int row0 = h * 1024 + it * 64;

        // ---- A fragments from swizzled LDS ----
        bf16x8 a[2][4];               // [mi][kk]
#pragma unroll
        for (int mi = 0; mi < 2; ++mi)
#pragma unroll
            for (int kk = 0; kk < 4; ++kk) {
                const int row  = wm * 32 + mi * 16 + r;
                const int slot = row * 16 + ((kk * 4 + g) ^ (row & 7));
                a[mi][kk] = *(const bf16x8*)&Als[lofs + slot * 8];
            }

        // ---- 32 MFMAs, operands swapped: D[n][m] (S^T tile) ----
        f32x4 acc[4][2] = {};         // [ni][mi]
#pragma unroll
        for (int kk = 0; kk < 4; ++kk)
#pragma unroll
            for (int ni = 0; ni < 4; ++ni)
#pragma unroll
                for (int mi = 0; mi < 2; ++mi)
                    acc[ni][mi] = __builtin_amdgcn_mfma_f32_16x16x32_bf16(b[ni][kk], a[mi][kk], acc[ni][mi], 0, 0, 0);

        // ---- epilogue: per-A-row max over this wave's 64 cols ----
        // Column m = mi*16 + r holds 16 n-values in regs -> 15 fmax + 2 shfl;
        // lanes 0-15 store one exclusive full 64B line per mi (R5 lesson).
#pragma unroll
        for (int mi = 0; mi < 2; ++mi) {
            float m = acc[0][mi][0];
#pragma unroll
            for (int ni = 0; ni < 4; ++ni)
#pragma unroll
                for (int rr = 0; rr < 4; ++rr)
                    if (ni || rr) m = fmaxf(m, acc[ni][mi][rr]);
            m = fmaxf(m, __shfl_xor(m, 16, 64));
            m = fmaxf(m, __shfl_xor(m, 32, 64));
            if (lane < 16)
                pmax_w[row0 + wm * 32 + mi * 16 + lane] = m;
        }

        // ---- diagonal min (anchor identity's own rows) ----
        // misel stays COMPILE-TIME into acc (R1: dynamic index -> scratch spill).
        if (diag_blk && it == itd && wm == wmsel) {
            float m = 3.4e38f;
#pragma unroll
            for (int mi = 0; mi < 2; ++mi) {
                if (mi == misel) {
#pragma unroll
                    for (int ni = 0; ni < 4; ++ni)
#pragma unroll
                        for (int rr = 0; rr < 4; ++rr)
                            m = fminf(m, acc[ni][mi][rr]);
                }
            }
            m = fminf(m, __shfl_xor(m, 16, 64));
            m = fminf(m, __shfl_xor(m, 32, 64));
            if (lane < 16)
                pmin[(size_t)wn * B_DIM + p * 16 + lane] = m;
        }

        if (it < 15) {
            // drain the 4 prefetch DMAs (oldest vmem); the 2 newest epilogue
            // stores stay in flight. vmcnt=2, expcnt=7, lgkmcnt=15 -> 0xF72.
            __builtin_amdgcn_s_waitcnt(0xF72);
            __builtin_amdgcn_s_barrier();
        }
        lofs ^= TSZ;
    }
}

// ---------------- kernel 3: per-row loss + mean ----------------
// grid 256 blocks x 256 threads; block = 16 rows. Lanes r=0..15 read 64B-line
// chunks of [p][row]; 16 p-groups partial-sum via LDS.
__global__ __launch_bounds__(256) void phase2(const float* __restrict__ pmax,  // [2][256][4096]
                                              const float* __restrict__ pmin,  // [2][4096]
                                              const int* __restrict__ labels,
                                              float* __restrict__ out) {
    const int tid = threadIdx.x;
    const int r   = tid & 15;
    const int pg  = tid >> 4;
    const int row = blockIdx.x * 16 + r;
    const int pid = labels[row];
    const float* q0 = pmax + row;                          // + p*B_DIM
    const float* q1 = q0 + (size_t)P_IDS * B_DIM;
    float s = 0.f;
#pragma unroll
    for (int j = 0; j < 16; ++j) {
        const int p = pg * 16 + j;
        const float v = fmaxf(q0[(size_t)p * B_DIM], q1[(size_t)p * B_DIM]);
        s += (p == pid) ? 0.f : __expf(v * INV_TEMP);
    }
    __shared__ float part[16][17];
    part[pg][r] = s;
    __syncthreads();
    if (tid < 16) {
        float neg = 0.f;
#pragma unroll
        for (int j = 0; j < 16; ++j) neg += part[j][tid];
        const int rw = blockIdx.x * 16 + tid;
        const float mn  = fminf(pmin[rw], pmin[B_DIM + rw]);
        const float pos = __expf(mn * INV_TEMP);
        float loss = -__logf(pos / (pos + neg + EPS) + EPS);
        loss += __shfl_xor(loss, 1, 64);
        loss += __shfl_xor(loss, 2, 64);
        loss += __shfl_xor(loss, 4, 64);
        loss += __shfl_xor(loss, 8, 64);
        if (tid == 0) atomicAdd(out, loss * (1.0f / (float)B_DIM));
    }
}

extern "C" void kernel_launch(void* const* d_in, const int* in_sizes, int n_in,
                              void* d_out, int out_size, void* d_ws, size_t ws_size,
                              hipStream_t stream) {
    const float* feats   = (const float*)d_in[0];   // [4096,128]
    const float* feats_s = (const float*)d_in[1];   // [4096,8,128] fp32 (read directly)
    const int*   labels  = (const int*)d_in[2];     // [4096]
    float* out = (float*)d_out;

    // workspace: bf16 A (1 MB) | pmax (8 MB) | pmin (32 KB)
    u16* wsA = (u16*)d_ws;
    float* pmax = (float*)((char*)d_ws + (1u << 20));
    float* pmin = pmax + (size_t)2 * P_IDS * B_DIM;

    hipMemsetAsync(d_out, 0, sizeof(float), stream);
    convert_bf16<<<NA4 / 256, 256, 0, stream>>>((const float4*)feats, wsA);
    dim3 g1(P_IDS, 4);
    phase1<<<g1, 256, 0, stream>>>(wsA, feats_s, pmax, pmin);
    phase2<<<B_DIM / 16, 256, 0, stream>>>(pmax, pmin, labels, out);
}